// Round 2
// baseline (290.737 us; speedup 1.0000x reference)
//
#include <hip/hip_runtime.h>
#include <cstdint>
#include <cstddef>

typedef unsigned short ushort_t;
typedef unsigned short ushort8 __attribute__((ext_vector_type(8)));
typedef __bf16 bf16x8 __attribute__((ext_vector_type(8)));
typedef float floatx4 __attribute__((ext_vector_type(4)));

#define N_TOK 8192
#define CDIM 1024
#define NEXP 8

__device__ __forceinline__ float bf2f(ushort_t h) {
  union { unsigned int u; float f; } v; v.u = ((unsigned int)h) << 16; return v.f;
}
__device__ __forceinline__ ushort_t f2bf(float f) {
  union { float f; unsigned int u; } v; v.f = f;
  unsigned int r = v.u + 0x7fffu + ((v.u >> 16) & 1u);
  return (ushort_t)(r >> 16);
}

// Async global->LDS, 16B per lane. LDS dest = base + lane*16 (HW-defined).
__device__ __forceinline__ void async_copy16(const ushort_t* g, ushort_t* l) {
  __builtin_amdgcn_global_load_lds(
      (const __attribute__((address_space(1))) unsigned int*)g,
      (__attribute__((address_space(3))) unsigned int*)l, 16, 0, 0);
}

// Input-dtype probe (f32 vs bf16) + zero the expert counters.
__global__ void detect_init_kernel(const ushort_t* __restrict__ x,
                                   int* __restrict__ flag,
                                   int* __restrict__ cnt) {
  int tid = threadIdx.x;  // 128 threads
  ushort_t u = x[tid];
  int ex = (u >> 7) & 0xFF;
  int crazy = (ex >= 0xC0 || ex <= 0x30) ? 1 : 0;
  int total = __syncthreads_count(crazy);
  if (tid == 0) flag[0] = (total >= 16) ? 1 : 0;
  if (tid < NEXP) cnt[tid] = 0;
}

// One wave per token: logits at native precision, top-2 (ties->lower idx),
// softmax over 2. Also emits the token row converted to bf16 (xbf) —
// the wave touches every element of the row anyway.
__global__ void router_compute(const void* __restrict__ xv,
                               const void* __restrict__ rwv,
                               const int* __restrict__ flag,
                               int* __restrict__ tok_e,
                               float* __restrict__ prob,
                               ushort_t* __restrict__ xbf) {
  int isf32 = flag[0];
  int wid = threadIdx.x >> 6;
  int lane = threadIdx.x & 63;
  int t = blockIdx.x * 4 + wid;

  float acc[NEXP];
#pragma unroll
  for (int e = 0; e < NEXP; e++) acc[e] = 0.f;

  if (isf32) {
    const float* xr = (const float*)xv + (size_t)t * CDIM;
    const float* rw = (const float*)rwv;
#pragma unroll
    for (int half = 0; half < 2; half++) {
      int base = (lane + half * 64) * 8;
      floatx4 x0 = *(const floatx4*)(xr + base);
      floatx4 x1 = *(const floatx4*)(xr + base + 4);
      ushort8 o;
#pragma unroll
      for (int i = 0; i < 4; i++) { o[i] = f2bf(x0[i]); o[4 + i] = f2bf(x1[i]); }
      *(ushort8*)(xbf + (size_t)t * CDIM + base) = o;
#pragma unroll
      for (int e = 0; e < NEXP; e++) {
        floatx4 w0 = *(const floatx4*)(rw + e * CDIM + base);
        floatx4 w1 = *(const floatx4*)(rw + e * CDIM + base + 4);
        acc[e] += x0[0]*w0[0] + x0[1]*w0[1] + x0[2]*w0[2] + x0[3]*w0[3]
                + x1[0]*w1[0] + x1[1]*w1[1] + x1[2]*w1[2] + x1[3]*w1[3];
      }
    }
  } else {
    const ushort_t* xr = (const ushort_t*)xv + (size_t)t * CDIM;
    const ushort_t* rw = (const ushort_t*)rwv;
#pragma unroll
    for (int half = 0; half < 2; half++) {
      int base = (lane + half * 64) * 8;
      ushort8 xu = *(const ushort8*)(xr + base);
      *(ushort8*)(xbf + (size_t)t * CDIM + base) = xu;
#pragma unroll
      for (int e = 0; e < NEXP; e++) {
        ushort8 wu = *(const ushort8*)(rw + e * CDIM + base);
#pragma unroll
        for (int i = 0; i < 8; i++) acc[e] += bf2f(xu[i]) * bf2f(wu[i]);
      }
    }
  }

#pragma unroll
  for (int e = 0; e < NEXP; e++) {
#pragma unroll
    for (int off = 32; off > 0; off >>= 1) acc[e] += __shfl_xor(acc[e], off);
  }

  if (lane == 0) {
    int e0 = 0; float l0 = acc[0];
#pragma unroll
    for (int e = 1; e < NEXP; e++) if (acc[e] > l0) { l0 = acc[e]; e0 = e; }
    int e1 = (e0 == 0) ? 1 : 0; float l1 = acc[e1];
#pragma unroll
    for (int e = 0; e < NEXP; e++) {
      if (e != e0 && acc[e] > l1) { l1 = acc[e]; e1 = e; }
    }
    float p0 = 1.f / (1.f + __expf(l1 - l0));  // l0 = max -> stable
    tok_e[t] = e0 | (e1 << 8);
    prob[t * 2] = p0;
    prob[t * 2 + 1] = 1.f - p0;
  }
}

// Build per-expert slot lists. 8 blocks x 1024 threads, 1024 tokens/block.
__global__ void scatter_kernel(const int* __restrict__ tok_e,
                               int* __restrict__ cnt,
                               int* __restrict__ slots) {
  __shared__ int lcnt[NEXP];
  __shared__ int gbase[NEXP];
  int tid = threadIdx.x;
  if (tid < NEXP) lcnt[tid] = 0;
  __syncthreads();
  int t = blockIdx.x * 1024 + tid;
  int ee = tok_e[t];
  int e0 = ee & 0xFF, e1 = (ee >> 8) & 0xFF;
  int lofs0 = atomicAdd(&lcnt[e0], 1);
  int lofs1 = atomicAdd(&lcnt[e1], 1);
  __syncthreads();
  if (tid < NEXP) gbase[tid] = atomicAdd(&cnt[tid], lcnt[tid]);
  __syncthreads();
  slots[e0 * N_TOK + gbase[e0] + lofs0] = t * 2;
  slots[e1 * N_TOK + gbase[e1] + lofs1] = t * 2 + 1;
}

// Transpose (+convert to bf16) 1024x1024: z<8 -> w1[z], else w2[z-8].
__global__ void transpose_kernel(const void* __restrict__ w1v,
                                 const void* __restrict__ w2v,
                                 const int* __restrict__ flag,
                                 ushort_t* __restrict__ w1T,
                                 ushort_t* __restrict__ w2T) {
  int isf32 = flag[0];
  int z = blockIdx.z;
  size_t moff = (size_t)(z & 7) << 20;
  const void* srcv = (z < 8) ? w1v : w2v;
  ushort_t* dst = ((z < 8) ? w1T : w2T) + moff;

  __shared__ __align__(16) ushort_t tile[64][72];
  int t = threadIdx.x;
  int R0 = blockIdx.y * 64, C0 = blockIdx.x * 64;
  int r = t >> 2, cb = (t & 3) * 16;
  if (isf32) {
    const float* sp = (const float*)srcv + moff + (size_t)(R0 + r) * 1024 + C0 + cb;
    ushort8 o0, o1;
#pragma unroll
    for (int q = 0; q < 2; q++) {
      floatx4 f = *(const floatx4*)(sp + q * 4);
#pragma unroll
      for (int i = 0; i < 4; i++) o0[q * 4 + i] = f2bf(f[i]);
    }
#pragma unroll
    for (int q = 0; q < 2; q++) {
      floatx4 f = *(const floatx4*)(sp + 8 + q * 4);
#pragma unroll
      for (int i = 0; i < 4; i++) o1[q * 4 + i] = f2bf(f[i]);
    }
    *(ushort8*)&tile[r][cb] = o0;
    *(ushort8*)&tile[r][cb + 8] = o1;
  } else {
    const ushort_t* sp = (const ushort_t*)srcv + moff + (size_t)(R0 + r) * 1024 + C0 + cb;
    *(ushort8*)&tile[r][cb] = *(const ushort8*)sp;
    *(ushort8*)&tile[r][cb + 8] = *(const ushort8*)(sp + 8);
  }
  __syncthreads();
  int d = t >> 2, rb = (t & 3) * 16;
  ushort8 o0, o1;
#pragma unroll
  for (int j = 0; j < 8; j++) { o0[j] = tile[rb + j][d]; o1[j] = tile[rb + 8 + j][d]; }
  ushort_t* dp = dst + (size_t)(C0 + d) * 1024 + R0 + rb;
  *(ushort8*)dp = o0;
  *(ushort8*)(dp + 8) = o1;
}

// Grouped GEMM, 256x128 tile, BK=32, 512 threads = 8 waves (4m x 2n of 64x64).
// DOUBLE-BUFFERED LDS + counted vmcnt (T3+T4): next K-tile's 3 global_load_lds
// are issued BEFORE computing the current tile, and s_waitcnt vmcnt(3) (never
// 0 in the main loop) lets them stay in flight across both raw s_barriers —
// staging latency hides under MFMA instead of serializing with it.
// Cross-wave safety: each wave's vmcnt(3) confirms its OWN current-tile loads
// landed; the s_barrier immediately after means all waves enter COMPUTE only
// after every wave has confirmed — HK/m201 counted-vmcnt pattern.
// XOR chunk swizzle (chunk ^ row&3) keeps ds_read_b128 conflict-free
// (enumerated: 8 lanes per (row-parity, chunk) bank-quad = 2 lanes/bank = free).
// Accumulation order over k is identical to the BK=64 version (bitwise-same).
// LDS = 2*16K(A) + 2*8K(B) + 1K(srow) = 50176 B -> 2 blocks/CU (VGPR<=128).
// MODE 0: hidden[slot] = relu(xbf[slot>>1] @ w1T[e]^T)^2
// MODE 1: oslots[slot] = prob[slot] * (hidden[slot] @ w2T[e]^T)
template <int MODE>
__global__ __launch_bounds__(512, 4) void moe_gemm(const ushort_t* __restrict__ A,
                                                   const ushort_t* __restrict__ BT,
                                                   ushort_t* __restrict__ Out,
                                                   const int* __restrict__ cnt,
                                                   const int* __restrict__ slots,
                                                   const float* __restrict__ prob) {
  int bid = blockIdx.x;
  int e = bid & 7;
  int nt = (bid >> 3) & 7;
  int mt = bid >> 6;
  int M = cnt[e];
  M = (M > N_TOK) ? N_TOK : M;
  int m0 = mt * 256;
  if (m0 >= M) return;
  int n0 = nt * 128;

  __shared__ __align__(16) ushort_t As[2][256 * 32];
  __shared__ __align__(16) ushort_t Bs[2][128 * 32];
  __shared__ int srow[256];

  int tid = threadIdx.x;
  if (tid < 256) {
    int gm = m0 + tid;
    int gi = (gm < M) ? gm : (M - 1);
    srow[tid] = slots[e * N_TOK + gi] & (2 * N_TOK - 1);
  }
  __syncthreads();

  int wid = tid >> 6;
  int lane = tid & 63;
  int lrow = lane >> 2;                  // 0..15: row within 16-row staging stripe
  int gchunk = (lane & 3) ^ (lrow & 3);  // swizzled 16B source chunk (0..3)

  // A: 2 stripes of 16 rows per wave (8 waves x 16 x 2 = 256 rows).
  // B: 1 stripe of 16 rows per wave (128 rows).
  const ushort_t* aptr[2];
  const ushort_t* bptr0;
#pragma unroll
  for (int j = 0; j < 2; j++) {
    int rr = j * 128 + wid * 16 + lrow;
    int s = srow[rr];
    int aidx = (MODE == 0) ? (s >> 1) : s;
    aptr[j] = A + (size_t)aidx * CDIM + gchunk * 8;
  }
  {
    int rr = wid * 16 + lrow;
    bptr0 = BT + ((size_t)e << 20) + (size_t)(n0 + rr) * 1024 + gchunk * 8;
  }

  int wm = (wid >> 1) * 64;   // 0,64,128,192
  int wn = (wid & 1) * 64;    // 0,64
  int qd = lane >> 4;         // 0..3: k-chunk of the MFMA fragment
  int ln = lane & 15;
  int l3 = ln & 3;
  int pc = (qd ^ l3) * 8;     // swizzled LDS chunk for fragment reads

  floatx4 zero = {0.f, 0.f, 0.f, 0.f};
  floatx4 acc[4][4];
#pragma unroll
  for (int i = 0; i < 4; i++)
#pragma unroll
    for (int j = 0; j < 4; j++) acc[i][j] = zero;

  // Stage one K-tile (BK=32): 2 A-loads + 1 B-load of 16B per thread.
#define STAGE(buf, kofs)                                                     \
  do {                                                                       \
    async_copy16(aptr[0] + (kofs), &As[buf][wid * 512]);                     \
    async_copy16(aptr[1] + (kofs), &As[buf][4096 + wid * 512]);              \
    async_copy16(bptr0 + (kofs), &Bs[buf][wid * 512]);                       \
  } while (0)

  // One K-step of compute from buffer cb: 8 ds_read_b128 + 16 MFMA.
#define COMPUTE(cb)                                                          \
  do {                                                                       \
    bf16x8 afr[4], bfr[4];                                                   \
    _Pragma("unroll")                                                        \
    for (int i = 0; i < 4; i++) {                                            \
      afr[i] = *(const bf16x8*)&As[cb][(wm + i * 16 + ln) * 32 + pc];        \
      bfr[i] = *(const bf16x8*)&Bs[cb][(wn + i * 16 + ln) * 32 + pc];        \
    }                                                                        \
    __builtin_amdgcn_s_setprio(1);                                           \
    _Pragma("unroll")                                                        \
    for (int i = 0; i < 4; i++)                                              \
      _Pragma("unroll")                                                      \
      for (int j = 0; j < 4; j++)                                            \
        acc[i][j] = __builtin_amdgcn_mfma_f32_16x16x32_bf16(afr[i], bfr[j],  \
                                                            acc[i][j], 0, 0, 0); \
    __builtin_amdgcn_s_setprio(0);                                           \
  } while (0)

  STAGE(0, 0);  // prologue: K-tile 0 in flight
  int cur = 0;
  for (int kt = 0; kt < 31; ++kt) {
    STAGE(cur ^ 1, (kt + 1) * 32);                    // next tile: 3 more in flight
    asm volatile("s_waitcnt vmcnt(3)" ::: "memory");  // current tile landed (per-wave)
    __builtin_amdgcn_s_barrier();                     // ... all waves confirmed
    COMPUTE(cur);                                     // overlaps next-tile loads
    asm volatile("s_waitcnt lgkmcnt(0)" ::: "memory");
    __builtin_amdgcn_s_barrier();                     // readers done before overwrite
    cur ^= 1;
  }
  asm volatile("s_waitcnt vmcnt(0)" ::: "memory");    // last tile landed
  __builtin_amdgcn_s_barrier();
  COMPUTE(cur);

#undef STAGE
#undef COMPUTE

  // C/D layout: col = lane&15, row = (lane>>4)*4 + reg  [m89]
#pragma unroll
  for (int i = 0; i < 4; i++) {
#pragma unroll
    for (int r = 0; r < 4; r++) {
      int rl = wm + i * 16 + qd * 4 + r;
      int gm = m0 + rl;
      if (gm >= M) continue;
      int s = srow[rl];
      float p = (MODE == 1) ? prob[s] : 0.f;
      ushort_t* orow = Out + (size_t)s * 1024 + n0 + wn + ln;
#pragma unroll
      for (int j = 0; j < 4; j++) {
        float v = acc[i][j][r];
        if (MODE == 0) { v = fmaxf(v, 0.f); v = v * v; }
        else v *= p;
        orow[j * 16] = f2bf(v);
      }
    }
  }
}

// out (FLOAT32) [t][c] = oslots[2t][c] + oslots[2t+1][c]
__global__ void combine_kernel(const ushort_t* __restrict__ oslots,
                               float* __restrict__ out) {
  int idx = (blockIdx.x * 256 + threadIdx.x) * 8;
  int t = idx >> 10;
  int c = idx & 1023;
  const ushort_t* r0 = oslots + ((size_t)t * 2) * 1024 + c;
  const ushort_t* r1 = r0 + 1024;
  ushort8 a = *(const ushort8*)r0;
  ushort8 b = *(const ushort8*)r1;
  floatx4 o0, o1;
#pragma unroll
  for (int i = 0; i < 4; i++) o0[i] = bf2f(a[i]) + bf2f(b[i]);
#pragma unroll
  for (int i = 0; i < 4; i++) o1[i] = bf2f(a[4 + i]) + bf2f(b[4 + i]);
  *(floatx4*)(out + idx) = o0;
  *(floatx4*)(out + idx + 4) = o1;
}

extern "C" void kernel_launch(void* const* d_in, const int* in_sizes, int n_in,
                              void* d_out, int out_size, void* d_ws, size_t ws_size,
                              hipStream_t stream) {
  const void* x  = d_in[0];
  const void* rw = d_in[1];
  const void* w1 = d_in[2];
  const void* w2 = d_in[3];
  float* out = (float*)d_out;
  char* ws = (char*)d_ws;

  int* cnt  = (int*)(ws + 0);                       // 32 B
  int* flag = (int*)(ws + 64);                      // 4 B
  int* slots = (int*)(ws + 1024);                   // 256 KiB
  float* prob = (float*)(ws + 263168);              // 64 KiB
  int* tok_e = (int*)(ws + 335872);                 // 32 KiB
  ushort_t* xbf = (ushort_t*)(ws + 524288);         // 16 MiB (dead after gemm0)
  ushort_t* w1T = (ushort_t*)(ws + 17301504);       // 16 MiB (dead after gemm0)
  ushort_t* hidden = (ushort_t*)(ws + 34078720);    // 32 MiB
  ushort_t* w2T = (ushort_t*)(ws + 67633152);       // 16 MiB -> high-water 84,410,368
  ushort_t* oslots = (ushort_t*)(ws + 524288);      // 32 MiB, aliases xbf+w1T

  detect_init_kernel<<<1, 128, 0, stream>>>((const ushort_t*)x, flag, cnt);
  router_compute<<<N_TOK / 4, 256, 0, stream>>>(x, rw, flag, tok_e, prob, xbf);
  scatter_kernel<<<NEXP, 1024, 0, stream>>>(tok_e, cnt, slots);
  transpose_kernel<<<dim3(16, 16, 16), 256, 0, stream>>>(w1, w2, flag, w1T, w2T);
  // grid: 32 m-tiles x 8 n-tiles x 8 experts, expert fastest (XCD affinity)
  moe_gemm<0><<<2048, 512, 0, stream>>>(xbf, w1T, hidden, cnt, slots, prob);
  moe_gemm<1><<<2048, 512, 0, stream>>>(hidden, w2T, oslots, cnt, slots, prob);
  combine_kernel<<<4096, 256, 0, stream>>>(oslots, out);
}

// Round 3
// 268.846 us; speedup vs baseline: 1.0814x; 1.0814x over previous
//
#include <hip/hip_runtime.h>
#include <cstdint>
#include <cstddef>

typedef unsigned short ushort_t;
typedef unsigned short ushort8 __attribute__((ext_vector_type(8)));
typedef __bf16 bf16x8 __attribute__((ext_vector_type(8)));
typedef float floatx4 __attribute__((ext_vector_type(4)));

#define N_TOK 8192
#define CDIM 1024
#define NEXP 8

__device__ __forceinline__ float bf2f(ushort_t h) {
  union { unsigned int u; float f; } v; v.u = ((unsigned int)h) << 16; return v.f;
}
__device__ __forceinline__ ushort_t f2bf(float f) {
  union { float f; unsigned int u; } v; v.f = f;
  unsigned int r = v.u + 0x7fffu + ((v.u >> 16) & 1u);
  return (ushort_t)(r >> 16);
}

// Async global->LDS, 16B per lane. LDS dest = base + lane*16 (HW-defined).
__device__ __forceinline__ void async_copy16(const ushort_t* g, ushort_t* l) {
  __builtin_amdgcn_global_load_lds(
      (const __attribute__((address_space(1))) unsigned int*)g,
      (__attribute__((address_space(3))) unsigned int*)l, 16, 0, 0);
}

// Input-dtype probe (f32 vs bf16) + zero the expert counters.
__global__ void detect_init_kernel(const ushort_t* __restrict__ x,
                                   int* __restrict__ flag,
                                   int* __restrict__ cnt) {
  int tid = threadIdx.x;  // 128 threads
  ushort_t u = x[tid];
  int ex = (u >> 7) & 0xFF;
  int crazy = (ex >= 0xC0 || ex <= 0x30) ? 1 : 0;
  int total = __syncthreads_count(crazy);
  if (tid == 0) flag[0] = (total >= 16) ? 1 : 0;
  if (tid < NEXP) cnt[tid] = 0;
}

// One wave per token: logits at native precision, top-2 (ties->lower idx),
// softmax over 2. Also emits the token row converted to bf16 (xbf) —
// the wave touches every element of the row anyway.
__global__ void router_compute(const void* __restrict__ xv,
                               const void* __restrict__ rwv,
                               const int* __restrict__ flag,
                               int* __restrict__ tok_e,
                               float* __restrict__ prob,
                               ushort_t* __restrict__ xbf) {
  int isf32 = flag[0];
  int wid = threadIdx.x >> 6;
  int lane = threadIdx.x & 63;
  int t = blockIdx.x * 4 + wid;

  float acc[NEXP];
#pragma unroll
  for (int e = 0; e < NEXP; e++) acc[e] = 0.f;

  if (isf32) {
    const float* xr = (const float*)xv + (size_t)t * CDIM;
    const float* rw = (const float*)rwv;
#pragma unroll
    for (int half = 0; half < 2; half++) {
      int base = (lane + half * 64) * 8;
      floatx4 x0 = *(const floatx4*)(xr + base);
      floatx4 x1 = *(const floatx4*)(xr + base + 4);
      ushort8 o;
#pragma unroll
      for (int i = 0; i < 4; i++) { o[i] = f2bf(x0[i]); o[4 + i] = f2bf(x1[i]); }
      *(ushort8*)(xbf + (size_t)t * CDIM + base) = o;
#pragma unroll
      for (int e = 0; e < NEXP; e++) {
        floatx4 w0 = *(const floatx4*)(rw + e * CDIM + base);
        floatx4 w1 = *(const floatx4*)(rw + e * CDIM + base + 4);
        acc[e] += x0[0]*w0[0] + x0[1]*w0[1] + x0[2]*w0[2] + x0[3]*w0[3]
                + x1[0]*w1[0] + x1[1]*w1[1] + x1[2]*w1[2] + x1[3]*w1[3];
      }
    }
  } else {
    const ushort_t* xr = (const ushort_t*)xv + (size_t)t * CDIM;
    const ushort_t* rw = (const ushort_t*)rwv;
#pragma unroll
    for (int half = 0; half < 2; half++) {
      int base = (lane + half * 64) * 8;
      ushort8 xu = *(const ushort8*)(xr + base);
      *(ushort8*)(xbf + (size_t)t * CDIM + base) = xu;
#pragma unroll
      for (int e = 0; e < NEXP; e++) {
        ushort8 wu = *(const ushort8*)(rw + e * CDIM + base);
#pragma unroll
        for (int i = 0; i < 8; i++) acc[e] += bf2f(xu[i]) * bf2f(wu[i]);
      }
    }
  }

#pragma unroll
  for (int e = 0; e < NEXP; e++) {
#pragma unroll
    for (int off = 32; off > 0; off >>= 1) acc[e] += __shfl_xor(acc[e], off);
  }

  if (lane == 0) {
    int e0 = 0; float l0 = acc[0];
#pragma unroll
    for (int e = 1; e < NEXP; e++) if (acc[e] > l0) { l0 = acc[e]; e0 = e; }
    int e1 = (e0 == 0) ? 1 : 0; float l1 = acc[e1];
#pragma unroll
    for (int e = 0; e < NEXP; e++) {
      if (e != e0 && acc[e] > l1) { l1 = acc[e]; e1 = e; }
    }
    float p0 = 1.f / (1.f + __expf(l1 - l0));  // l0 = max -> stable
    tok_e[t] = e0 | (e1 << 8);
    prob[t * 2] = p0;
    prob[t * 2 + 1] = 1.f - p0;
  }
}

// Build per-expert slot lists. 8 blocks x 1024 threads, 1024 tokens/block.
__global__ void scatter_kernel(const int* __restrict__ tok_e,
                               int* __restrict__ cnt,
                               int* __restrict__ slots) {
  __shared__ int lcnt[NEXP];
  __shared__ int gbase[NEXP];
  int tid = threadIdx.x;
  if (tid < NEXP) lcnt[tid] = 0;
  __syncthreads();
  int t = blockIdx.x * 1024 + tid;
  int ee = tok_e[t];
  int e0 = ee & 0xFF, e1 = (ee >> 8) & 0xFF;
  int lofs0 = atomicAdd(&lcnt[e0], 1);
  int lofs1 = atomicAdd(&lcnt[e1], 1);
  __syncthreads();
  if (tid < NEXP) gbase[tid] = atomicAdd(&cnt[tid], lcnt[tid]);
  __syncthreads();
  slots[e0 * N_TOK + gbase[e0] + lofs0] = t * 2;
  slots[e1 * N_TOK + gbase[e1] + lofs1] = t * 2 + 1;
}

// Transpose (+convert to bf16) 1024x1024: z<8 -> w1[z], else w2[z-8].
__global__ void transpose_kernel(const void* __restrict__ w1v,
                                 const void* __restrict__ w2v,
                                 const int* __restrict__ flag,
                                 ushort_t* __restrict__ w1T,
                                 ushort_t* __restrict__ w2T) {
  int isf32 = flag[0];
  int z = blockIdx.z;
  size_t moff = (size_t)(z & 7) << 20;
  const void* srcv = (z < 8) ? w1v : w2v;
  ushort_t* dst = ((z < 8) ? w1T : w2T) + moff;

  __shared__ __align__(16) ushort_t tile[64][72];
  int t = threadIdx.x;
  int R0 = blockIdx.y * 64, C0 = blockIdx.x * 64;
  int r = t >> 2, cb = (t & 3) * 16;
  if (isf32) {
    const float* sp = (const float*)srcv + moff + (size_t)(R0 + r) * 1024 + C0 + cb;
    ushort8 o0, o1;
#pragma unroll
    for (int q = 0; q < 2; q++) {
      floatx4 f = *(const floatx4*)(sp + q * 4);
#pragma unroll
      for (int i = 0; i < 4; i++) o0[q * 4 + i] = f2bf(f[i]);
    }
#pragma unroll
    for (int q = 0; q < 2; q++) {
      floatx4 f = *(const floatx4*)(sp + 8 + q * 4);
#pragma unroll
      for (int i = 0; i < 4; i++) o1[q * 4 + i] = f2bf(f[i]);
    }
    *(ushort8*)&tile[r][cb] = o0;
    *(ushort8*)&tile[r][cb + 8] = o1;
  } else {
    const ushort_t* sp = (const ushort_t*)srcv + moff + (size_t)(R0 + r) * 1024 + C0 + cb;
    *(ushort8*)&tile[r][cb] = *(const ushort8*)sp;
    *(ushort8*)&tile[r][cb + 8] = *(const ushort8*)(sp + 8);
  }
  __syncthreads();
  int d = t >> 2, rb = (t & 3) * 16;
  ushort8 o0, o1;
#pragma unroll
  for (int j = 0; j < 8; j++) { o0[j] = tile[rb + j][d]; o1[j] = tile[rb + 8 + j][d]; }
  ushort_t* dp = dst + (size_t)(C0 + d) * 1024 + R0 + rb;
  *(ushort8*)dp = o0;
  *(ushort8*)(dp + 8) = o1;
}

// Grouped GEMM, 256x128 tile, BK=32, 512 threads = 8 waves (4m x 2n of 64x64).
// TRIPLE-BUFFERED LDS + depth-2 counted-vmcnt prefetch (T3+T4): tiles t+1 and
// t+2 stay in flight while computing tile t. vmcnt(6) = 9 outstanding minus
// the landed oldest tile (3 loads/tile). Two K-steps of compute (~1400 cyc)
// cover the HBM gather latency (~900 cyc) that depth-1 could not.
// Conflict-free swizzle (fixed from round 1): chunk c of row r stored at
// position c ^ ((r>>1)&3). Bank-quad = 4*(row&1) + pos is then a bijection
// onto 0..7 within every 8-consecutive-lane issue group of ds_read_b128
// (round-1's c ^ (r&3) gave 2 addresses/quad -> 4.45M conflict cycles).
// Accumulation order over k identical to round-0 (bitwise-same output).
// LDS = 3*16K(A) + 3*8K(B) + 1K(srow) = 74752 B -> 2 blocks/CU.
// No setprio: m190 shows it is null-to-negative on barrier-lockstep GEMM.
// MODE 0: hidden[slot] = relu(xbf[slot>>1] @ w1T[e]^T)^2
// MODE 1: oslots[slot] = prob[slot] * (hidden[slot] @ w2T[e]^T)
template <int MODE>
__global__ __launch_bounds__(512, 4) void moe_gemm(const ushort_t* __restrict__ A,
                                                   const ushort_t* __restrict__ BT,
                                                   ushort_t* __restrict__ Out,
                                                   const int* __restrict__ cnt,
                                                   const int* __restrict__ slots,
                                                   const float* __restrict__ prob) {
  int bid = blockIdx.x;
  int e = bid & 7;
  int nt = (bid >> 3) & 7;
  int mt = bid >> 6;
  int M = cnt[e];
  M = (M > N_TOK) ? N_TOK : M;
  int m0 = mt * 256;
  if (m0 >= M) return;
  int n0 = nt * 128;

  __shared__ __align__(16) ushort_t As[3][256 * 32];
  __shared__ __align__(16) ushort_t Bs[3][128 * 32];
  __shared__ int srow[256];

  int tid = threadIdx.x;
  if (tid < 256) {
    int gm = m0 + tid;
    int gi = (gm < M) ? gm : (M - 1);
    srow[tid] = slots[e * N_TOK + gi] & (2 * N_TOK - 1);
  }
  __syncthreads();

  int wid = tid >> 6;
  int lane = tid & 63;
  int lrow = lane >> 2;                        // 0..15: row within 16-row stripe
  int gchunk = (lane & 3) ^ ((lrow >> 1) & 3); // swizzled 16B source chunk

  // A: 2 stripes of 16 rows per wave (8 waves x 16 x 2 = 256 rows).
  // B: 1 stripe of 16 rows per wave (128 rows).
  const ushort_t* aptr[2];
  const ushort_t* bptr0;
#pragma unroll
  for (int j = 0; j < 2; j++) {
    int rr = j * 128 + wid * 16 + lrow;
    int s = srow[rr];
    int aidx = (MODE == 0) ? (s >> 1) : s;
    aptr[j] = A + (size_t)aidx * CDIM + gchunk * 8;
  }
  {
    int rr = wid * 16 + lrow;
    bptr0 = BT + ((size_t)e << 20) + (size_t)(n0 + rr) * 1024 + gchunk * 8;
  }

  int wm = (wid >> 1) * 64;   // 0,64,128,192
  int wn = (wid & 1) * 64;    // 0,64
  int qd = lane >> 4;         // 0..3: k-chunk of the MFMA fragment
  int ln = lane & 15;
  int pc = (qd ^ ((ln >> 1) & 3)) * 8;  // swizzled LDS chunk for fragment reads

  floatx4 zero = {0.f, 0.f, 0.f, 0.f};
  floatx4 acc[4][4];
#pragma unroll
  for (int i = 0; i < 4; i++)
#pragma unroll
    for (int j = 0; j < 4; j++) acc[i][j] = zero;

  // Stage one K-tile (BK=32) into buffer b: 2 A-loads + 1 B-load of 16B/thread.
#define STAGE(b, tile)                                                       \
  do {                                                                       \
    async_copy16(aptr[0] + (tile) * 32, &As[b][wid * 512]);                  \
    async_copy16(aptr[1] + (tile) * 32, &As[b][4096 + wid * 512]);           \
    async_copy16(bptr0 + (tile) * 32, &Bs[b][wid * 512]);                    \
  } while (0)

  // One K-step of compute from buffer cb: 8 ds_read_b128 + 16 MFMA.
#define COMPUTE(cb)                                                          \
  do {                                                                       \
    bf16x8 afr[4], bfr[4];                                                   \
    _Pragma("unroll")                                                        \
    for (int i = 0; i < 4; i++) {                                            \
      afr[i] = *(const bf16x8*)&As[cb][(wm + i * 16 + ln) * 32 + pc];        \
      bfr[i] = *(const bf16x8*)&Bs[cb][(wn + i * 16 + ln) * 32 + pc];        \
    }                                                                        \
    _Pragma("unroll")                                                        \
    for (int i = 0; i < 4; i++)                                              \
      _Pragma("unroll")                                                      \
      for (int j = 0; j < 4; j++)                                            \
        acc[i][j] = __builtin_amdgcn_mfma_f32_16x16x32_bf16(afr[i], bfr[j],  \
                                                            acc[i][j], 0, 0, 0); \
  } while (0)

#define VMCNT(n) asm volatile("s_waitcnt vmcnt(" #n ")" ::: "memory")
#define LGKM0()  asm volatile("s_waitcnt lgkmcnt(0)" ::: "memory")
#define BAR()    __builtin_amdgcn_s_barrier()

  // Prologue: tiles 0 and 1 in flight (6 loads).
  STAGE(0, 0);
  STAGE(1, 1);
  // Steady state: 30 tiles, unroll x3 for static buffer indices.
  for (int it = 0; it < 10; ++it) {
    int kt = it * 3;
    STAGE(2, kt + 2); VMCNT(6); BAR(); COMPUTE(0); LGKM0(); BAR();
    STAGE(0, kt + 3); VMCNT(6); BAR(); COMPUTE(1); LGKM0(); BAR();
    STAGE(1, kt + 4); VMCNT(6); BAR(); COMPUTE(2); LGKM0(); BAR();
  }
  // Tail: tiles 30 (buf 0) and 31 (buf 1); nothing overwrites -> no LGKM/BAR
  // after the computes (epilogue reads only registers + srow).
  VMCNT(3); BAR(); COMPUTE(0);
  VMCNT(0); BAR(); COMPUTE(1);

#undef STAGE
#undef COMPUTE
#undef VMCNT
#undef LGKM0
#undef BAR

  // C/D layout: col = lane&15, row = (lane>>4)*4 + reg  [m89]
#pragma unroll
  for (int i = 0; i < 4; i++) {
#pragma unroll
    for (int r = 0; r < 4; r++) {
      int rl = wm + i * 16 + qd * 4 + r;
      int gm = m0 + rl;
      if (gm >= M) continue;
      int s = srow[rl];
      float p = (MODE == 1) ? prob[s] : 0.f;
      ushort_t* orow = Out + (size_t)s * 1024 + n0 + wn + ln;
#pragma unroll
      for (int j = 0; j < 4; j++) {
        float v = acc[i][j][r];
        if (MODE == 0) { v = fmaxf(v, 0.f); v = v * v; }
        else v *= p;
        orow[j * 16] = f2bf(v);
      }
    }
  }
}

// out (FLOAT32) [t][c] = oslots[2t][c] + oslots[2t+1][c]
__global__ void combine_kernel(const ushort_t* __restrict__ oslots,
                               float* __restrict__ out) {
  int idx = (blockIdx.x * 256 + threadIdx.x) * 8;
  int t = idx >> 10;
  int c = idx & 1023;
  const ushort_t* r0 = oslots + ((size_t)t * 2) * 1024 + c;
  const ushort_t* r1 = r0 + 1024;
  ushort8 a = *(const ushort8*)r0;
  ushort8 b = *(const ushort8*)r1;
  floatx4 o0, o1;
#pragma unroll
  for (int i = 0; i < 4; i++) o0[i] = bf2f(a[i]) + bf2f(b[i]);
#pragma unroll
  for (int i = 0; i < 4; i++) o1[i] = bf2f(a[4 + i]) + bf2f(b[4 + i]);
  *(floatx4*)(out + idx) = o0;
  *(floatx4*)(out + idx + 4) = o1;
}

extern "C" void kernel_launch(void* const* d_in, const int* in_sizes, int n_in,
                              void* d_out, int out_size, void* d_ws, size_t ws_size,
                              hipStream_t stream) {
  const void* x  = d_in[0];
  const void* rw = d_in[1];
  const void* w1 = d_in[2];
  const void* w2 = d_in[3];
  float* out = (float*)d_out;
  char* ws = (char*)d_ws;

  int* cnt  = (int*)(ws + 0);                       // 32 B
  int* flag = (int*)(ws + 64);                      // 4 B
  int* slots = (int*)(ws + 1024);                   // 256 KiB
  float* prob = (float*)(ws + 263168);              // 64 KiB
  int* tok_e = (int*)(ws + 335872);                 // 32 KiB
  ushort_t* xbf = (ushort_t*)(ws + 524288);         // 16 MiB (dead after gemm0)
  ushort_t* w1T = (ushort_t*)(ws + 17301504);       // 16 MiB (dead after gemm0)
  ushort_t* hidden = (ushort_t*)(ws + 34078720);    // 32 MiB
  ushort_t* w2T = (ushort_t*)(ws + 67633152);       // 16 MiB -> high-water 84,410,368
  ushort_t* oslots = (ushort_t*)(ws + 524288);      // 32 MiB, aliases xbf+w1T

  detect_init_kernel<<<1, 128, 0, stream>>>((const ushort_t*)x, flag, cnt);
  router_compute<<<N_TOK / 4, 256, 0, stream>>>(x, rw, flag, tok_e, prob, xbf);
  scatter_kernel<<<NEXP, 1024, 0, stream>>>(tok_e, cnt, slots);
  transpose_kernel<<<dim3(16, 16, 16), 256, 0, stream>>>(w1, w2, flag, w1T, w2T);
  // grid: 32 m-tiles x 8 n-tiles x 8 experts, expert fastest (XCD affinity)
  moe_gemm<0><<<2048, 512, 0, stream>>>(xbf, w1T, hidden, cnt, slots, prob);
  moe_gemm<1><<<2048, 512, 0, stream>>>(hidden, w2T, oslots, cnt, slots, prob);
  combine_kernel<<<4096, 256, 0, stream>>>(oslots, out);
}